// Round 8
// baseline (106.062 us; speedup 1.0000x reference)
//
#include <hip/hip_runtime.h>
#include <math.h>

// ImprovedSpeMamba: b*c*h = 32768 rows; each row = W=128 floats = 4 tokens x 32
#define NROWS 32768
#define NTILES 8192        // 4 rows per wave-tile
#define THREADS 256
#define WPB 4

typedef __attribute__((ext_vector_type(8))) __bf16 bf16x8;
typedef __attribute__((ext_vector_type(4))) float f32x4;
typedef __attribute__((ext_vector_type(2))) float f32x2;

__device__ __forceinline__ float silu_f(float v) {
    return v * __builtin_amdgcn_rcpf(1.f + __expf(-v));
}
// CDNA packed-f32 (VOP3P): 2 f32 lanes per issue slot, full rate.
__device__ __forceinline__ f32x2 pk_fma(f32x2 a, f32x2 b, f32x2 c) {
    f32x2 d;
    asm("v_pk_fma_f32 %0, %1, %2, %3" : "=v"(d) : "v"(a), "v"(b), "v"(c));
    return d;
}
__device__ __forceinline__ f32x2 pk_mul(f32x2 a, f32x2 b) {
    f32x2 d;
    asm("v_pk_mul_f32 %0, %1, %2" : "=v"(d) : "v"(a), "v"(b));
    return d;
}
#define VLO(v) __builtin_shufflevector((v), (v), 0, 1)
#define VHI(v) __builtin_shufflevector((v), (v), 2, 3)

// ---------------------------------------------------------------------------
// K1: fused mamba. Wave = 4 rows (M=16 tokens). GEMMs via mfma 16x16x32 bf16.
// xc / silu(z) staged in LDS as bf16. LDS = 35840 B -> 4 blocks/CU.
// Scan: pk_fma pairs (R7) + b128 B/C reads (R8: 18->7 DS ops per scan step).
// NO min-waves launch bound (R5: it forced 64 VGPR + scratch spills).
// ---------------------------------------------------------------------------
__global__ __launch_bounds__(256) void k_mamba(
    const float* __restrict__ x,
    const float* __restrict__ in_proj_w,   // (128,32)
    const float* __restrict__ conv_w,      // (64,4)
    const float* __restrict__ conv_b,      // (64)
    const float* __restrict__ x_proj_w,    // (34,64)
    const float* __restrict__ dt_proj_w,   // (64,2)
    const float* __restrict__ dt_proj_b,   // (64)
    const float* __restrict__ A_log,       // (64,16)
    const float* __restrict__ Dvec,        // (64)
    const float* __restrict__ out_proj_w,  // (32,64)
    float* __restrict__ xr,                // d_out as xr scratch
    float* __restrict__ S1, float* __restrict__ S2)
{
    __shared__ __align__(16) __bf16 b1f[8*64*8];          // 8 KiB B1 frags
    __shared__ __align__(16) __bf16 xcb[WPB][16*72];      // xc, later y (bf16)
    __shared__ __align__(16) __bf16 szb[WPB][16*72];      // silu(z) (bf16)
    __shared__ __align__(16) float  dbb[WPB][16*36];      // dbl rows (f32)

    const int tid  = threadIdx.x;
    const int wid  = tid >> 6;
    const int lane = tid & 63;
    const int c = lane & 15;      // A-row / B-col / D-col within 16-tile
    const int q = lane >> 4;      // K-octet selector / D-row group

    // ---- stage B1 frags (bf16): lane: col j=c, k=8q+i
    for (int idx = tid; idx < 512; idx += THREADS) {
        int jt = idx >> 6, l = idx & 63, cc = l & 15, qq = l >> 4;
        const float* src = in_proj_w + (jt*16 + cc)*32 + qq*8;
        bf16x8 v;
        #pragma unroll
        for (int i = 0; i < 8; ++i) v[i] = (__bf16)src[i];
        *((bf16x8*)(b1f) + idx) = v;
    }

    // ---- B2 (x_proj) frags in regs: col r = rt*16+c, k = ks*32+8q+i
    bf16x8 B2f[2][3];
    #pragma unroll
    for (int ks = 0; ks < 2; ++ks)
        #pragma unroll
        for (int rt = 0; rt < 3; ++rt) {
            int row = rt*16 + c;
            #pragma unroll
            for (int i = 0; i < 8; ++i)
                B2f[ks][rt][i] = (row < 34) ? (__bf16)x_proj_w[row*64 + ks*32 + q*8 + i]
                                            : (__bf16)0.f;
        }
    // ---- B3 (out_proj) frags
    bf16x8 B3f[2][2];   // [jt][ks]
    #pragma unroll
    for (int jt = 0; jt < 2; ++jt)
        #pragma unroll
        for (int ks = 0; ks < 2; ++ks) {
            int row = jt*16 + c;
            #pragma unroll
            for (int i = 0; i < 8; ++i)
                B3f[jt][ks][i] = (__bf16)out_proj_w[row*64 + ks*32 + q*8 + i];
        }

    // ---- per-lane params
    float cwj[4][4], cbj[4];
    #pragma unroll
    for (int jt = 0; jt < 4; ++jt) {
        int d = jt*16 + c;
        #pragma unroll
        for (int k = 0; k < 4; ++k) cwj[jt][k] = conv_w[d*4 + k];
        cbj[jt] = conv_b[d];
    }
    const float dtw0 = dt_proj_w[lane*2+0], dtw1 = dt_proj_w[lane*2+1];
    const float dtb  = dt_proj_b[lane];
    const float Dd   = Dvec[lane];

    // ---- fast-A check: A_log == log(1..16) (wave-uniform)
    bool okl = true;
    #pragma unroll
    for (int s = 0; s < 16; ++s) {
        float a = __expf(A_log[lane*16 + s]);
        okl = okl && (fabsf(a - (float)(s+1)) < 1e-3f * (float)(s+1));
    }
    const bool fastA = (__ballot(okl) == ~0ull);

    __syncthreads();

    __bf16* xc_ = xcb[wid];
    __bf16* sz_ = szb[wid];
    float*  db_ = dbb[wid];
    const bf16x8* B1p = (const bf16x8*)b1f;
    const int nwaves = gridDim.x * WPB;

    for (int tile = blockIdx.x*WPB + wid; tile < NTILES; tile += nwaves) {
        const int n0 = tile * 4;                 // 4 rows, same (b,c) plane
        const float* xrow = x + n0*128;

        // ---- A1 frag from global (x row-contiguous), f32 -> bf16
        bf16x8 A1;
        {
            const float4* xp4 = (const float4*)(xrow + c*32 + q*8);
            float4 a = xp4[0], b = xp4[1];
            A1[0]=(__bf16)a.x; A1[1]=(__bf16)a.y; A1[2]=(__bf16)a.z; A1[3]=(__bf16)a.w;
            A1[4]=(__bf16)b.x; A1[5]=(__bf16)b.y; A1[6]=(__bf16)b.z; A1[7]=(__bf16)b.w;
        }

        // ---- GEMM1 (8 jt) + conv/silu in D-layout (reg = token)
        #pragma unroll
        for (int jt = 0; jt < 8; ++jt) {
            f32x4 acc = {0.f, 0.f, 0.f, 0.f};
            acc = __builtin_amdgcn_mfma_f32_16x16x32_bf16(A1, B1p[jt*64 + lane], acc, 0, 0, 0);
            if (jt < 4) {
                const float* cw = cwj[jt];
                float cb = cbj[jt];
                float xc0 = cb + cw[3]*acc[0];
                float xc1 = cb + cw[2]*acc[0] + cw[3]*acc[1];
                float xc2 = cb + cw[1]*acc[0] + cw[2]*acc[1] + cw[3]*acc[2];
                float xc3 = cb + cw[0]*acc[0] + cw[1]*acc[1] + cw[2]*acc[2] + cw[3]*acc[3];
                int dcol = jt*16 + c;
                xc_[(4*q+0)*72 + dcol] = (__bf16)silu_f(xc0);
                xc_[(4*q+1)*72 + dcol] = (__bf16)silu_f(xc1);
                xc_[(4*q+2)*72 + dcol] = (__bf16)silu_f(xc2);
                xc_[(4*q+3)*72 + dcol] = (__bf16)silu_f(xc3);
            } else {
                int dcol = (jt-4)*16 + c;
                #pragma unroll
                for (int t = 0; t < 4; ++t)
                    sz_[(4*q+t)*72 + dcol] = (__bf16)silu_f(acc[t]);
            }
        }

        // ---- A2 frags: direct bf16x8 loads from xc
        bf16x8 A2[2];
        #pragma unroll
        for (int ks = 0; ks < 2; ++ks)
            A2[ks] = *(const bf16x8*)&xc_[c*72 + ks*32 + q*8];

        // ---- GEMM2: dbl[m][r]
        f32x4 dacc[3] = {{0,0,0,0},{0,0,0,0},{0,0,0,0}};
        #pragma unroll
        for (int ks = 0; ks < 2; ++ks) {
            dacc[0] = __builtin_amdgcn_mfma_f32_16x16x32_bf16(A2[ks], B2f[ks][0], dacc[0], 0,0,0);
            dacc[1] = __builtin_amdgcn_mfma_f32_16x16x32_bf16(A2[ks], B2f[ks][1], dacc[1], 0,0,0);
            dacc[2] = __builtin_amdgcn_mfma_f32_16x16x32_bf16(A2[ks], B2f[ks][2], dacc[2], 0,0,0);
        }
        // stage dbl: db_[m*36 + 2 + r], r = rt*16+c.
        // GUARD r < 34 EXACTLY (c<2 at rt==2): stride-36 rows spill otherwise.
        #pragma unroll
        for (int rt = 0; rt < 3; ++rt) {
            if (rt < 2 || c < 2) {
                #pragma unroll
                for (int t = 0; t < 4; ++t)
                    db_[(4*q+t)*36 + 2 + rt*16 + c] = dacc[rt][t];
            }
        }

        // ---- selective scan, lane = d, rows sequential; pk-f32 pairs,
        // B/C fetched as b128 (4+4 per step) and pair-aliased in regs.
        #pragma unroll
        for (int r = 0; r < 4; ++r) {
            f32x2 h2[8];
            #pragma unroll
            for (int s = 0; s < 8; ++s) h2[s] = (f32x2){0.f, 0.f};
            #pragma unroll
            for (int t = 0; t < 4; ++t) {
                const int m = 4*r + t;
                float2 dtv = *(const float2*)&db_[m*36 + 2];
                float p  = fmaf(dtv.y, dtw1, fmaf(dtv.x, dtw0, dtb));
                float ex = __expf(p);
                float t1 = 1.f + ex;
                float e1 = __builtin_amdgcn_rcpf(t1);       // exp(-softplus(p)) exactly
                float delta = (p > 15.f) ? p : __logf(t1);  // softplus(p)
                float u  = (float)xc_[m*72 + lane];
                float sz = (float)sz_[m*72 + lane];
                const float bu = delta * u;
                const f32x2 bu2 = {bu, bu};

                // dA pairs: {e^1,e^2}, {e^3,e^4}, ... via pk_mul chain by {e^2,e^2}
                f32x2 dA2[8];
                if (fastA) {
                    float e2 = e1 * e1;
                    dA2[0][0] = e1; dA2[0][1] = e2;
                    f32x2 ee = {e2, e2};
                    #pragma unroll
                    for (int i = 1; i < 8; ++i) dA2[i] = pk_mul(dA2[i-1], ee);
                } else {
                    #pragma unroll
                    for (int s = 0; s < 16; ++s)
                        dA2[s>>1][s&1] = __expf(-delta * __expf(A_log[lane*16 + s]));
                }

                // b128 loads (4 for B, 4 for C), pair views are register aliases
                const f32x4* B4 = (const f32x4*)&db_[m*36 + 4];
                const f32x4* C4 = (const f32x4*)&db_[m*36 + 20];
                f32x4 bv0 = B4[0], bv1 = B4[1], bv2 = B4[2], bv3 = B4[3];
                f32x4 cv0 = C4[0], cv1 = C4[1], cv2 = C4[2], cv3 = C4[3];
                f32x2 Bp[8] = {VLO(bv0), VHI(bv0), VLO(bv1), VHI(bv1),
                               VLO(bv2), VHI(bv2), VLO(bv3), VHI(bv3)};
                f32x2 Cp[8] = {VLO(cv0), VHI(cv0), VLO(cv1), VHI(cv1),
                               VLO(cv2), VHI(cv2), VLO(cv3), VHI(cv3)};

                f32x2 accA = {0.f, 0.f}, accB = {0.f, 0.f};
                #pragma unroll
                for (int i = 0; i < 8; ++i) {
                    h2[i] = pk_fma(dA2[i], h2[i], pk_mul(bu2, Bp[i]));
                    if (i & 1) accB = pk_fma(h2[i], Cp[i], accB);
                    else       accA = pk_fma(h2[i], Cp[i], accA);
                }
                float acc = (accA[0] + accA[1]) + (accB[0] + accB[1]);
                float y = fmaf(u, Dd, acc) * sz;
                xc_[m*72 + lane] = (__bf16)y;    // overlay xc with gated y
            }
        }

        // ---- A3 frags from y (direct bf16x8) + GEMM3 + store + stats
        bf16x8 A3[2];
        #pragma unroll
        for (int ks = 0; ks < 2; ++ks)
            A3[ks] = *(const bf16x8*)&xc_[c*72 + ks*32 + q*8];

        float s1 = 0.f, s2 = 0.f;
        float* orow = xr + n0*128;
        #pragma unroll
        for (int jt = 0; jt < 2; ++jt) {
            f32x4 oacc = {0.f, 0.f, 0.f, 0.f};
            oacc = __builtin_amdgcn_mfma_f32_16x16x32_bf16(A3[0], B3f[jt][0], oacc, 0,0,0);
            oacc = __builtin_amdgcn_mfma_f32_16x16x32_bf16(A3[1], B3f[jt][1], oacc, 0,0,0);
            #pragma unroll
            for (int t = 0; t < 4; ++t) {
                orow[(4*q+t)*32 + jt*16 + c] = oacc[t];
                s1 += oacc[t];
                s2 += oacc[t]*oacc[t];
            }
        }
        #pragma unroll
        for (int off = 32; off > 0; off >>= 1) {
            s1 += __shfl_xor(s1, off, 64);
            s2 += __shfl_xor(s2, off, 64);
        }
        if (lane == 0) {
            atomicAdd(&S1[tile >> 5], s1);
            atomicAdd(&S2[tile >> 5], s2);
        }
    }
}

// ---------------------------------------------------------------------------
// K2: fused SE+GN prologue (per block, redundant but tiny) + elementwise
// out = silu(alpha*xr + beta) + x   (in-place on d_out)
// ---------------------------------------------------------------------------
__global__ __launch_bounds__(256) void k_final(
    const float* __restrict__ x, float* __restrict__ o,
    const float* __restrict__ S1, const float* __restrict__ S2,
    const float* __restrict__ se1_w,  // (32,128)
    const float* __restrict__ se2_w,  // (128,32)
    const float* __restrict__ gn_w, const float* __restrict__ gn_b)
{
    __shared__ float sp[256], sh[64], sg[256], st1[256], st2[256];
    __shared__ float smu[8], sinv[8];
    __shared__ float al[256], be[256];
    const int tid = threadIdx.x;

    sp[tid] = S1[tid] * (1.f/16384.f);
    __syncthreads();

    if (tid < 64) {
        int b = tid >> 5, j = tid & 31;
        float acc = 0.f;
        for (int cc = 0; cc < 128; ++cc) acc += sp[b*128 + cc] * se1_w[j*128 + cc];
        sh[tid] = silu_f(acc);
    }
    __syncthreads();

    {
        int b = tid >> 7, cc = tid & 127;
        float acc = 0.f;
        #pragma unroll
        for (int j = 0; j < 32; ++j) acc += sh[b*32 + j] * se2_w[cc*32 + j];
        float g = __builtin_amdgcn_rcpf(1.f + __expf(-acc));
        sg[tid]  = g;
        st1[tid] = g * S1[tid];
        st2[tid] = g * g * S2[tid];
    }
    __syncthreads();

    if (tid < 8) {
        int b = tid >> 2, gr = tid & 3;
        float m = 0.f, qq = 0.f;
        for (int cc = 0; cc < 32; ++cc) {
            m  += st1[b*128 + gr*32 + cc];
            qq += st2[b*128 + gr*32 + cc];
        }
        const float inv_cnt = 1.f / (32.f * 16384.f);
        m *= inv_cnt; qq *= inv_cnt;
        smu[tid]  = m;
        sinv[tid] = rsqrtf(qq - m*m + 1e-5f);
    }
    __syncthreads();

    {
        int b = tid >> 7, cc = tid & 127;
        int gi = b*4 + (cc >> 5);
        float iv = sinv[gi], mu = smu[gi], g = sg[tid], w = gn_w[cc];
        al[tid] = g * iv * w;
        be[tid] = gn_b[cc] - mu * iv * w;
    }
    __syncthreads();

    const int total4 = (2*128*128*128) / 4;
    const float4* x4 = (const float4*)x;
    float4* o4 = (float4*)o;
    for (int i = blockIdx.x*blockDim.x + tid; i < total4;
         i += gridDim.x*blockDim.x) {
        int bc = i >> 12;
        float a = al[bc], b = be[bc];
        float4 v = o4[i], xv = x4[i];
        float u;
        u = a*v.x + b;  v.x = silu_f(u) + xv.x;
        u = a*v.y + b;  v.y = silu_f(u) + xv.y;
        u = a*v.z + b;  v.z = silu_f(u) + xv.z;
        u = a*v.w + b;  v.w = silu_f(u) + xv.w;
        o4[i] = v;
    }
}

extern "C" void kernel_launch(void* const* d_in, const int* in_sizes, int n_in,
                              void* d_out, int out_size, void* d_ws, size_t ws_size,
                              hipStream_t stream) {
    const float* x          = (const float*)d_in[0];
    const float* in_proj_w  = (const float*)d_in[1];
    const float* conv_w     = (const float*)d_in[2];
    const float* conv_b     = (const float*)d_in[3];
    const float* x_proj_w   = (const float*)d_in[4];
    const float* dt_proj_w  = (const float*)d_in[5];
    const float* dt_proj_b  = (const float*)d_in[6];
    const float* A_log      = (const float*)d_in[7];
    const float* Dvec       = (const float*)d_in[8];
    const float* out_proj_w = (const float*)d_in[9];
    const float* se1_w      = (const float*)d_in[10];
    const float* se2_w      = (const float*)d_in[11];
    const float* gn_w       = (const float*)d_in[12];
    const float* gn_b       = (const float*)d_in[13];

    float* out = (float*)d_out;
    float* ws  = (float*)d_ws;
    float* S1 = ws;           // 256
    float* S2 = ws + 256;     // 256

    hipMemsetAsync(ws, 0, 512*sizeof(float), stream);
    k_mamba<<<2048, THREADS, 0, stream>>>(x, in_proj_w, conv_w, conv_b, x_proj_w,
                                          dt_proj_w, dt_proj_b, A_log, Dvec,
                                          out_proj_w, out, S1, S2);
    k_final<<<2048, THREADS, 0, stream>>>(x, out, S1, S2, se1_w, se2_w, gn_w, gn_b);
}

// Round 9
// 84.273 us; speedup vs baseline: 1.2585x; 1.2585x over previous
//
#include <hip/hip_runtime.h>
#include <math.h>

// ImprovedSpeMamba: b*c*h = 32768 rows; each row = W=128 floats = 4 tokens x 32
#define NTILES 8192        // 4 rows per wave-tile
#define THREADS 256
#define WPB 4

typedef __attribute__((ext_vector_type(8))) __bf16 bf16x8;
typedef __attribute__((ext_vector_type(4))) float f32x4;
typedef __attribute__((ext_vector_type(2))) float f32x2;

__device__ __forceinline__ float silu_f(float v) {
    return v * __builtin_amdgcn_rcpf(1.f + __expf(-v));
}
__device__ __forceinline__ f32x2 pk_fma(f32x2 a, f32x2 b, f32x2 c) {
    f32x2 d;
    asm("v_pk_fma_f32 %0, %1, %2, %3" : "=v"(d) : "v"(a), "v"(b), "v"(c));
    return d;
}
__device__ __forceinline__ f32x2 pk_mul(f32x2 a, f32x2 b) {
    f32x2 d;
    asm("v_pk_mul_f32 %0, %1, %2" : "=v"(d) : "v"(a), "v"(b));
    return d;
}
#define VLO(v) __builtin_shufflevector((v), (v), 0, 1)
#define VHI(v) __builtin_shufflevector((v), (v), 2, 3)

__device__ __forceinline__ bf16x8 cvt8v(float4 a, float4 b) {
    bf16x8 r;
    r[0]=(__bf16)a.x; r[1]=(__bf16)a.y; r[2]=(__bf16)a.z; r[3]=(__bf16)a.w;
    r[4]=(__bf16)b.x; r[5]=(__bf16)b.y; r[6]=(__bf16)b.z; r[7]=(__bf16)b.w;
    return r;
}

// log(1..16) for the fastA check (no exps in setup)
__device__ __constant__ float kLogTab[16] = {
    0.0f, 0.69314718f, 1.09861229f, 1.38629436f,
    1.60943791f, 1.79175947f, 1.94591015f, 2.07944154f,
    2.19722458f, 2.30258509f, 2.39789527f, 2.48490665f,
    2.56494936f, 2.63905733f, 2.70805020f, 2.77258872f};

// ---------------------------------------------------------------------------
// K1: fused mamba. Wave = 4 rows (M=16 tokens). GEMMs via mfma 16x16x32 bf16.
// Scan: 2 rows in flight (latency ILP), pk-f32 pairs, on-the-fly dA powers.
// B1/B3 frags in LDS; B2 frags in regs. LDS = 39936 B -> 4 blocks/CU.
// NO min-waves bound (R5 spill lesson). Grid 768 (2.67 tiles/wave).
// ---------------------------------------------------------------------------
__global__ __launch_bounds__(256) void k_mamba(
    const float* __restrict__ x,
    const float* __restrict__ in_proj_w,   // (128,32)
    const float* __restrict__ conv_w,      // (64,4)
    const float* __restrict__ conv_b,      // (64)
    const float* __restrict__ x_proj_w,    // (34,64)
    const float* __restrict__ dt_proj_w,   // (64,2)
    const float* __restrict__ dt_proj_b,   // (64)
    const float* __restrict__ A_log,       // (64,16)
    const float* __restrict__ Dvec,        // (64)
    const float* __restrict__ out_proj_w,  // (32,64)
    float* __restrict__ xr,                // d_out as xr scratch
    float* __restrict__ S1, float* __restrict__ S2)
{
    __shared__ __align__(16) __bf16 b1f[8*64*8];          // 8 KiB  B1 frags
    __shared__ __align__(16) __bf16 b3f[4*64*8];          // 4 KiB  B3 frags
    __shared__ __align__(16) __bf16 xcb[WPB][16*72];      // xc, later y (bf16)
    __shared__ __align__(16) __bf16 szb[WPB][16*72];      // silu(z) (bf16)
    __shared__ __align__(16) float  dbb[WPB][16*36];      // dbl rows (f32)

    const int tid  = threadIdx.x;
    const int wid  = tid >> 6;
    const int lane = tid & 63;
    const int c = lane & 15;      // token col within 16-tile
    const int q = lane >> 4;      // K-octet selector / D-row group

    // ---- stage B1 frags (float4 loads, bf16 stores)
    for (int idx = tid; idx < 512; idx += THREADS) {
        int jt = idx >> 6, l = idx & 63, cc = l & 15, qq = l >> 4;
        const float4* src = (const float4*)(in_proj_w + (jt*16 + cc)*32 + qq*8);
        *((bf16x8*)b1f + idx) = cvt8v(src[0], src[1]);
    }
    // ---- stage B3 frags: [jt][ks] x 64 lanes
    {
        int idx = tid;  // 256 items, one per thread
        int jt = idx >> 7, ks = (idx >> 6) & 1, l = idx & 63, cc = l & 15, qq = l >> 4;
        const float4* src = (const float4*)(out_proj_w + (jt*16 + cc)*64 + ks*32 + qq*8);
        *((bf16x8*)b3f + (jt*2 + ks)*64 + l) = cvt8v(src[0], src[1]);
    }

    // ---- B2 (x_proj) frags in regs: col r = rt*16+c, k = ks*32+8q+i
    bf16x8 B2f[2][3];
    #pragma unroll
    for (int ks = 0; ks < 2; ++ks)
        #pragma unroll
        for (int rt = 0; rt < 3; ++rt) {
            int row = rt*16 + c;
            if (row < 34) {
                const float4* p = (const float4*)(x_proj_w + row*64 + ks*32 + q*8);
                B2f[ks][rt] = cvt8v(p[0], p[1]);
            } else {
                #pragma unroll
                for (int i = 0; i < 8; ++i) B2f[ks][rt][i] = (__bf16)0.f;
            }
        }

    // ---- per-lane params (vector loads)
    float cwj[4][4], cbj[4];
    #pragma unroll
    for (int jt = 0; jt < 4; ++jt) {
        int d = jt*16 + c;
        float4 cw4 = *(const float4*)(conv_w + d*4);
        cwj[jt][0]=cw4.x; cwj[jt][1]=cw4.y; cwj[jt][2]=cw4.z; cwj[jt][3]=cw4.w;
        cbj[jt] = conv_b[d];
    }
    const float2 dtw = *(const float2*)(dt_proj_w + lane*2);
    const float dtbv = dt_proj_b[lane];
    const float Dd   = Dvec[lane];

    // ---- fast-A check: A_log == log(1..16)? (table compare, no exps)
    bool okl = true;
    #pragma unroll
    for (int s4 = 0; s4 < 4; ++s4) {
        float4 av = *(const float4*)(A_log + lane*16 + s4*4);
        okl = okl && fabsf(av.x - kLogTab[s4*4+0]) < 1e-4f
                  && fabsf(av.y - kLogTab[s4*4+1]) < 1e-4f
                  && fabsf(av.z - kLogTab[s4*4+2]) < 1e-4f
                  && fabsf(av.w - kLogTab[s4*4+3]) < 1e-4f;
    }
    const bool fastA = (__ballot(okl) == ~0ull);

    __syncthreads();

    __bf16* xc_ = xcb[wid];
    __bf16* sz_ = szb[wid];
    float*  db_ = dbb[wid];
    const bf16x8* B1p = (const bf16x8*)b1f;
    const bf16x8* B3p = (const bf16x8*)b3f;
    const int nwaves = gridDim.x * WPB;

    for (int tile = blockIdx.x*WPB + wid; tile < NTILES; tile += nwaves) {
        const int n0 = tile * 4;                 // 4 rows, same (b,c) plane
        const float* xrow = x + n0*128;

        // ---- A1 frag from global (x row-contiguous), f32 -> bf16
        const float4* xp4 = (const float4*)(xrow + c*32 + q*8);
        bf16x8 A1 = cvt8v(xp4[0], xp4[1]);

        // ---- GEMM1 (8 jt) + conv/silu in D-layout (reg = token)
        #pragma unroll
        for (int jt = 0; jt < 8; ++jt) {
            f32x4 acc = {0.f, 0.f, 0.f, 0.f};
            acc = __builtin_amdgcn_mfma_f32_16x16x32_bf16(A1, B1p[jt*64 + lane], acc, 0, 0, 0);
            if (jt < 4) {
                const float* cw = cwj[jt];
                float cb = cbj[jt];
                float xc0 = cb + cw[3]*acc[0];
                float xc1 = cb + cw[2]*acc[0] + cw[3]*acc[1];
                float xc2 = cb + cw[1]*acc[0] + cw[2]*acc[1] + cw[3]*acc[2];
                float xc3 = cb + cw[0]*acc[0] + cw[1]*acc[1] + cw[2]*acc[2] + cw[3]*acc[3];
                int dcol = jt*16 + c;
                xc_[(4*q+0)*72 + dcol] = (__bf16)silu_f(xc0);
                xc_[(4*q+1)*72 + dcol] = (__bf16)silu_f(xc1);
                xc_[(4*q+2)*72 + dcol] = (__bf16)silu_f(xc2);
                xc_[(4*q+3)*72 + dcol] = (__bf16)silu_f(xc3);
            } else {
                int dcol = (jt-4)*16 + c;
                #pragma unroll
                for (int t = 0; t < 4; ++t)
                    sz_[(4*q+t)*72 + dcol] = (__bf16)silu_f(acc[t]);
            }
        }

        // ---- A2 frags: direct bf16x8 loads from xc
        bf16x8 A2[2];
        #pragma unroll
        for (int ks = 0; ks < 2; ++ks)
            A2[ks] = *(const bf16x8*)&xc_[c*72 + ks*32 + q*8];

        // ---- GEMM2: dbl[m][r]
        f32x4 dacc[3] = {{0,0,0,0},{0,0,0,0},{0,0,0,0}};
        #pragma unroll
        for (int ks = 0; ks < 2; ++ks) {
            dacc[0] = __builtin_amdgcn_mfma_f32_16x16x32_bf16(A2[ks], B2f[ks][0], dacc[0], 0,0,0);
            dacc[1] = __builtin_amdgcn_mfma_f32_16x16x32_bf16(A2[ks], B2f[ks][1], dacc[1], 0,0,0);
            dacc[2] = __builtin_amdgcn_mfma_f32_16x16x32_bf16(A2[ks], B2f[ks][2], dacc[2], 0,0,0);
        }
        // stage dbl: db_[m*36 + 2 + r], r = rt*16+c. GUARD r < 34 EXACTLY.
        #pragma unroll
        for (int rt = 0; rt < 3; ++rt) {
            if (rt < 2 || c < 2) {
                #pragma unroll
                for (int t = 0; t < 4; ++t)
                    db_[(4*q+t)*36 + 2 + rt*16 + c] = dacc[rt][t];
            }
        }

        // ---- selective scan: 2 rows in flight, lane = d, pk-f32 pairs
        #pragma unroll
        for (int rp = 0; rp < 2; ++rp) {
            f32x2 hA[8], hB[8];
            #pragma unroll
            for (int s = 0; s < 8; ++s) { hA[s] = (f32x2){0.f,0.f}; hB[s] = (f32x2){0.f,0.f}; }
            #pragma unroll
            for (int t = 0; t < 4; ++t) {
                const int ma = rp*8 + t;       // row 2rp
                const int mb = ma + 4;         // row 2rp+1
                float2 dva = *(const float2*)&db_[ma*36 + 2];
                float2 dvb = *(const float2*)&db_[mb*36 + 2];
                float ua = (float)xc_[ma*72 + lane];
                float ub = (float)xc_[mb*72 + lane];
                float sa = (float)sz_[ma*72 + lane];
                float sb = (float)sz_[mb*72 + lane];
                float pA = fmaf(dva.y, dtw.y, fmaf(dva.x, dtw.x, dtbv));
                float pB = fmaf(dvb.y, dtw.y, fmaf(dvb.x, dtw.x, dtbv));
                float exA = __expf(pA), exB = __expf(pB);
                float t1A = 1.f + exA, t1B = 1.f + exB;
                float e1A = __builtin_amdgcn_rcpf(t1A);   // exp(-softplus) exactly
                float e1B = __builtin_amdgcn_rcpf(t1B);
                float dlA = (pA > 15.f) ? pA : __logf(t1A);
                float dlB = (pB > 15.f) ? pB : __logf(t1B);
                float buA = dlA * ua, buB = dlB * ub;
                const f32x2 buA2 = {buA, buA}, buB2 = {buB, buB};

                f32x2 acA0={0.f,0.f}, acA1={0.f,0.f}, acB0={0.f,0.f}, acB1={0.f,0.f};
                float accAsc = 0.f, accBsc = 0.f;
                if (fastA) {
                    float e2A = e1A*e1A, e2B = e1B*e1B;
                    f32x2 dcA = {e1A, e2A}, eeA = {e2A, e2A};
                    f32x2 dcB = {e1B, e2B}, eeB = {e2B, e2B};
                    #pragma unroll
                    for (int hf = 0; hf < 2; ++hf) {
                        const f32x4* BA4 = (const f32x4*)&db_[ma*36 + 4 + hf*8];
                        const f32x4* CA4 = (const f32x4*)&db_[ma*36 + 20 + hf*8];
                        const f32x4* BB4 = (const f32x4*)&db_[mb*36 + 4 + hf*8];
                        const f32x4* CB4 = (const f32x4*)&db_[mb*36 + 20 + hf*8];
                        f32x4 ba0 = BA4[0], ba1 = BA4[1], ca0 = CA4[0], ca1 = CA4[1];
                        f32x4 bb0 = BB4[0], bb1 = BB4[1], cb0 = CB4[0], cb1 = CB4[1];
                        f32x2 BpA[4] = {VLO(ba0), VHI(ba0), VLO(ba1), VHI(ba1)};
                        f32x2 CpA[4] = {VLO(ca0), VHI(ca0), VLO(ca1), VHI(ca1)};
                        f32x2 BpB[4] = {VLO(bb0), VHI(bb0), VLO(bb1), VHI(bb1)};
                        f32x2 CpB[4] = {VLO(cb0), VHI(cb0), VLO(cb1), VHI(cb1)};
                        #pragma unroll
                        for (int i = 0; i < 4; ++i) {
                            int idx = hf*4 + i;
                            hA[idx] = pk_fma(dcA, hA[idx], pk_mul(buA2, BpA[i]));
                            hB[idx] = pk_fma(dcB, hB[idx], pk_mul(buB2, BpB[i]));
                            if (hf) { acA1 = pk_fma(hA[idx], CpA[i], acA1);
                                      acB1 = pk_fma(hB[idx], CpB[i], acB1); }
                            else    { acA0 = pk_fma(hA[idx], CpA[i], acA0);
                                      acB0 = pk_fma(hB[idx], CpB[i], acB0); }
                            dcA = pk_mul(dcA, eeA);    // advance powers for next idx
                            dcB = pk_mul(dcB, eeB);
                        }
                    }
                } else {
                    #pragma unroll
                    for (int s = 0; s < 16; ++s) {
                        float aAbs = __expf(A_log[lane*16 + s]);
                        float dAa = __expf(-dlA * aAbs), dAb = __expf(-dlB * aAbs);
                        float Bma = db_[ma*36 + 4 + s], Cma = db_[ma*36 + 20 + s];
                        float Bmb = db_[mb*36 + 4 + s], Cmb = db_[mb*36 + 20 + s];
                        float hva = dAa * hA[s>>1][s&1] + buA * Bma;
                        hA[s>>1][s&1] = hva;  accAsc += hva * Cma;
                        float hvb = dAb * hB[s>>1][s&1] + buB * Bmb;
                        hB[s>>1][s&1] = hvb;  accBsc += hvb * Cmb;
                    }
                }
                float accA = (acA0[0]+acA0[1]) + (acA1[0]+acA1[1]) + accAsc;
                float accB = (acB0[0]+acB0[1]) + (acB1[0]+acB1[1]) + accBsc;
                float yA = fmaf(ua, Dd, accA) * sa;
                float yB = fmaf(ub, Dd, accB) * sb;
                xc_[ma*72 + lane] = (__bf16)yA;    // overlay xc with gated y
                xc_[mb*72 + lane] = (__bf16)yB;
            }
        }

        // ---- A3 frags from y (direct bf16x8) + GEMM3 + store + stats
        bf16x8 A3[2];
        #pragma unroll
        for (int ks = 0; ks < 2; ++ks)
            A3[ks] = *(const bf16x8*)&xc_[c*72 + ks*32 + q*8];

        float s1 = 0.f, s2 = 0.f;
        float* orow = xr + n0*128;
        #pragma unroll
        for (int jt = 0; jt < 2; ++jt) {
            f32x4 oacc = {0.f, 0.f, 0.f, 0.f};
            oacc = __builtin_amdgcn_mfma_f32_16x16x32_bf16(A3[0], B3p[(jt*2+0)*64 + lane], oacc, 0,0,0);
            oacc = __builtin_amdgcn_mfma_f32_16x16x32_bf16(A3[1], B3p[(jt*2+1)*64 + lane], oacc, 0,0,0);
            #pragma unroll
            for (int t = 0; t < 4; ++t) {
                orow[(4*q+t)*32 + jt*16 + c] = oacc[t];
                s1 += oacc[t];
                s2 += oacc[t]*oacc[t];
            }
        }
        #pragma unroll
        for (int off = 32; off > 0; off >>= 1) {
            s1 += __shfl_xor(s1, off, 64);
            s2 += __shfl_xor(s2, off, 64);
        }
        if (lane == 0) {
            atomicAdd(&S1[tile >> 5], s1);
            atomicAdd(&S2[tile >> 5], s2);
        }
    }
}

// ---------------------------------------------------------------------------
// K2: fused SE+GN prologue (per block, redundant but tiny) + elementwise
// out = silu(alpha*xr + beta) + x   (in-place on d_out)
// ---------------------------------------------------------------------------
__global__ __launch_bounds__(256) void k_final(
    const float* __restrict__ x, float* __restrict__ o,
    const float* __restrict__ S1, const float* __restrict__ S2,
    const float* __restrict__ se1_w,  // (32,128)
    const float* __restrict__ se2_w,  // (128,32)
    const float* __restrict__ gn_w, const float* __restrict__ gn_b)
{
    __shared__ float sp[256], sh[64], sg[256], st1[256], st2[256];
    __shared__ float smu[8], sinv[8];
    __shared__ float al[256], be[256];
    const int tid = threadIdx.x;

    sp[tid] = S1[tid] * (1.f/16384.f);
    __syncthreads();

    if (tid < 64) {
        int b = tid >> 5, j = tid & 31;
        float acc = 0.f;
        for (int cc = 0; cc < 128; ++cc) acc += sp[b*128 + cc] * se1_w[j*128 + cc];
        sh[tid] = silu_f(acc);
    }
    __syncthreads();

    {
        int b = tid >> 7, cc = tid & 127;
        float acc = 0.f;
        #pragma unroll
        for (int j = 0; j < 32; ++j) acc += sh[b*32 + j] * se2_w[cc*32 + j];
        float g = __builtin_amdgcn_rcpf(1.f + __expf(-acc));
        sg[tid]  = g;
        st1[tid] = g * S1[tid];
        st2[tid] = g * g * S2[tid];
    }
    __syncthreads();

    if (tid < 8) {
        int b = tid >> 2, gr = tid & 3;
        float m = 0.f, qq = 0.f;
        for (int cc = 0; cc < 32; ++cc) {
            m  += st1[b*128 + gr*32 + cc];
            qq += st2[b*128 + gr*32 + cc];
        }
        const float inv_cnt = 1.f / (32.f * 16384.f);
        m *= inv_cnt; qq *= inv_cnt;
        smu[tid]  = m;
        sinv[tid] = rsqrtf(qq - m*m + 1e-5f);
    }
    __syncthreads();

    {
        int b = tid >> 7, cc = tid & 127;
        int gi = b*4 + (cc >> 5);
        float iv = sinv[gi], mu = smu[gi], g = sg[tid], w = gn_w[cc];
        al[tid] = g * iv * w;
        be[tid] = gn_b[cc] - mu * iv * w;
    }
    __syncthreads();

    const int total4 = (2*128*128*128) / 4;
    const float4* x4 = (const float4*)x;
    float4* o4 = (float4*)o;
    for (int i = blockIdx.x*blockDim.x + tid; i < total4;
         i += gridDim.x*blockDim.x) {
        int bc = i >> 12;
        float a = al[bc], b = be[bc];
        float4 v = o4[i], xv = x4[i];
        float u;
        u = a*v.x + b;  v.x = silu_f(u) + xv.x;
        u = a*v.y + b;  v.y = silu_f(u) + xv.y;
        u = a*v.z + b;  v.z = silu_f(u) + xv.z;
        u = a*v.w + b;  v.w = silu_f(u) + xv.w;
        o4[i] = v;
    }
}

extern "C" void kernel_launch(void* const* d_in, const int* in_sizes, int n_in,
                              void* d_out, int out_size, void* d_ws, size_t ws_size,
                              hipStream_t stream) {
    const float* x          = (const float*)d_in[0];
    const float* in_proj_w  = (const float*)d_in[1];
    const float* conv_w     = (const float*)d_in[2];
    const float* conv_b     = (const float*)d_in[3];
    const float* x_proj_w   = (const float*)d_in[4];
    const float* dt_proj_w  = (const float*)d_in[5];
    const float* dt_proj_b  = (const float*)d_in[6];
    const float* A_log      = (const float*)d_in[7];
    const float* Dvec       = (const float*)d_in[8];
    const float* out_proj_w = (const float*)d_in[9];
    const float* se1_w      = (const float*)d_in[10];
    const float* se2_w      = (const float*)d_in[11];
    const float* gn_w       = (const float*)d_in[12];
    const float* gn_b       = (const float*)d_in[13];

    float* out = (float*)d_out;
    float* ws  = (float*)d_ws;
    float* S1 = ws;           // 256
    float* S2 = ws + 256;     // 256

    hipMemsetAsync(ws, 0, 512*sizeof(float), stream);
    k_mamba<<<768, THREADS, 0, stream>>>(x, in_proj_w, conv_w, conv_b, x_proj_w,
                                         dt_proj_w, dt_proj_b, A_log, Dvec,
                                         out_proj_w, out, S1, S2);
    k_final<<<2048, THREADS, 0, stream>>>(x, out, S1, S2, se1_w, se2_w, gn_w, gn_b);
}

// Round 10
// 78.035 us; speedup vs baseline: 1.3591x; 1.0799x over previous
//
#include <hip/hip_runtime.h>
#include <math.h>

// ImprovedSpeMamba: b*c*h = 32768 rows; each row = W=128 floats = 4 tokens x 32
#define NTILES 8192        // 4 rows per wave-tile
#define THREADS 256
#define WPB 4

typedef __attribute__((ext_vector_type(8))) __bf16 bf16x8;
typedef __attribute__((ext_vector_type(4))) float f32x4;
typedef __attribute__((ext_vector_type(2))) float f32x2;

__device__ __forceinline__ float silu_f(float v) {
    return v * __builtin_amdgcn_rcpf(1.f + __expf(-v));
}
__device__ __forceinline__ f32x2 pk_fma(f32x2 a, f32x2 b, f32x2 c) {
    f32x2 d;
    asm("v_pk_fma_f32 %0, %1, %2, %3" : "=v"(d) : "v"(a), "v"(b), "v"(c));
    return d;
}
__device__ __forceinline__ f32x2 pk_mul(f32x2 a, f32x2 b) {
    f32x2 d;
    asm("v_pk_mul_f32 %0, %1, %2" : "=v"(d) : "v"(a), "v"(b));
    return d;
}
// bf16-pair (one u32) -> f32x2 : lo = u<<16, hi = u & 0xffff0000
__device__ __forceinline__ f32x2 upk(unsigned u) {
    f32x2 r;
    r[0] = __uint_as_float(u << 16);
    r[1] = __uint_as_float(u & 0xffff0000u);
    return r;
}
__device__ __forceinline__ bf16x8 cvt8v(float4 a, float4 b) {
    bf16x8 r;
    r[0]=(__bf16)a.x; r[1]=(__bf16)a.y; r[2]=(__bf16)a.z; r[3]=(__bf16)a.w;
    r[4]=(__bf16)b.x; r[5]=(__bf16)b.y; r[6]=(__bf16)b.z; r[7]=(__bf16)b.w;
    return r;
}

// log(1..16) for the fastA check (no exps in setup)
__device__ __constant__ float kLogTab[16] = {
    0.0f, 0.69314718f, 1.09861229f, 1.38629436f,
    1.60943791f, 1.79175947f, 1.94591015f, 2.07944154f,
    2.19722458f, 2.30258509f, 2.39789527f, 2.48490665f,
    2.56494936f, 2.63905733f, 2.70805020f, 2.77258872f};

// ---------------------------------------------------------------------------
// K1: fused mamba. Wave = 4 rows (M=16 tokens). GEMMs via mfma 16x16x32 bf16.
// dbl staged as {f32 dt[2], bf16 B[16], bf16 C[16]} per m (80B row): scan
// reads 1 b64 + 4 b128 per step (was 1+8) -- DS is the CU-shared bottleneck.
// ---------------------------------------------------------------------------
__global__ __launch_bounds__(256) void k_mamba(
    const float* __restrict__ x,
    const float* __restrict__ in_proj_w,   // (128,32)
    const float* __restrict__ conv_w,      // (64,4)
    const float* __restrict__ conv_b,      // (64)
    const float* __restrict__ x_proj_w,    // (34,64)
    const float* __restrict__ dt_proj_w,   // (64,2)
    const float* __restrict__ dt_proj_b,   // (64)
    const float* __restrict__ A_log,       // (64,16)
    const float* __restrict__ Dvec,        // (64)
    const float* __restrict__ out_proj_w,  // (32,64)
    float* __restrict__ xr,                // d_out as xr scratch
    float* __restrict__ S1, float* __restrict__ S2)
{
    __shared__ __align__(16) __bf16 b1f[8*64*8];          // 8 KiB  B1 frags
    __shared__ __align__(16) __bf16 b3f[4*64*8];          // 4 KiB  B3 frags
    __shared__ __align__(16) __bf16 xcb[WPB][16*72];      // xc, later y (bf16)
    __shared__ __align__(16) __bf16 szb[WPB][16*72];      // silu(z) (bf16)
    __shared__ __align__(16) float  dbb[WPB][16*20];      // dbl rows (mixed, 80B)

    const int tid  = threadIdx.x;
    const int wid  = tid >> 6;
    const int lane = tid & 63;
    const int c = lane & 15;      // token col within 16-tile
    const int q = lane >> 4;      // K-octet selector / D-row group

    // ---- stage B1 frags
    for (int idx = tid; idx < 512; idx += THREADS) {
        int jt = idx >> 6, l = idx & 63, cc = l & 15, qq = l >> 4;
        const float4* src = (const float4*)(in_proj_w + (jt*16 + cc)*32 + qq*8);
        *((bf16x8*)b1f + idx) = cvt8v(src[0], src[1]);
    }
    // ---- stage B3 frags
    {
        int idx = tid;
        int jt = idx >> 7, ks = (idx >> 6) & 1, l = idx & 63, cc = l & 15, qq = l >> 4;
        const float4* src = (const float4*)(out_proj_w + (jt*16 + cc)*64 + ks*32 + qq*8);
        *((bf16x8*)b3f + (jt*2 + ks)*64 + l) = cvt8v(src[0], src[1]);
    }

    // ---- B2 (x_proj) frags in regs
    bf16x8 B2f[2][3];
    #pragma unroll
    for (int ks = 0; ks < 2; ++ks)
        #pragma unroll
        for (int rt = 0; rt < 3; ++rt) {
            int row = rt*16 + c;
            if (row < 34) {
                const float4* p = (const float4*)(x_proj_w + row*64 + ks*32 + q*8);
                B2f[ks][rt] = cvt8v(p[0], p[1]);
            } else {
                #pragma unroll
                for (int i = 0; i < 8; ++i) B2f[ks][rt][i] = (__bf16)0.f;
            }
        }

    // ---- per-lane params
    float cwj[4][4], cbj[4];
    #pragma unroll
    for (int jt = 0; jt < 4; ++jt) {
        int d = jt*16 + c;
        float4 cw4 = *(const float4*)(conv_w + d*4);
        cwj[jt][0]=cw4.x; cwj[jt][1]=cw4.y; cwj[jt][2]=cw4.z; cwj[jt][3]=cw4.w;
        cbj[jt] = conv_b[d];
    }
    const float2 dtw = *(const float2*)(dt_proj_w + lane*2);
    const float dtbv = dt_proj_b[lane];
    const float Dd   = Dvec[lane];

    // ---- fast-A check (table compare)
    bool okl = true;
    #pragma unroll
    for (int s4 = 0; s4 < 4; ++s4) {
        float4 av = *(const float4*)(A_log + lane*16 + s4*4);
        okl = okl && fabsf(av.x - kLogTab[s4*4+0]) < 1e-4f
                  && fabsf(av.y - kLogTab[s4*4+1]) < 1e-4f
                  && fabsf(av.z - kLogTab[s4*4+2]) < 1e-4f
                  && fabsf(av.w - kLogTab[s4*4+3]) < 1e-4f;
    }
    const bool fastA = (__ballot(okl) == ~0ull);

    __syncthreads();

    __bf16* xc_ = xcb[wid];
    __bf16* sz_ = szb[wid];
    float*  db_ = dbb[wid];
    __bf16* dbh = (__bf16*)db_;            // bf16 view: row m at idx m*40
    const bf16x8* B1p = (const bf16x8*)b1f;
    const bf16x8* B3p = (const bf16x8*)b3f;
    const int nwaves = gridDim.x * WPB;

    for (int tile = blockIdx.x*WPB + wid; tile < NTILES; tile += nwaves) {
        const int n0 = tile * 4;
        const float* xrow = x + n0*128;

        // ---- A1 frag
        const float4* xp4 = (const float4*)(xrow + c*32 + q*8);
        bf16x8 A1 = cvt8v(xp4[0], xp4[1]);

        // ---- GEMM1 (8 jt) + conv/silu
        #pragma unroll
        for (int jt = 0; jt < 8; ++jt) {
            f32x4 acc = {0.f, 0.f, 0.f, 0.f};
            acc = __builtin_amdgcn_mfma_f32_16x16x32_bf16(A1, B1p[jt*64 + lane], acc, 0, 0, 0);
            if (jt < 4) {
                const float* cw = cwj[jt];
                float cb = cbj[jt];
                float xc0 = cb + cw[3]*acc[0];
                float xc1 = cb + cw[2]*acc[0] + cw[3]*acc[1];
                float xc2 = cb + cw[1]*acc[0] + cw[2]*acc[1] + cw[3]*acc[2];
                float xc3 = cb + cw[0]*acc[0] + cw[1]*acc[1] + cw[2]*acc[2] + cw[3]*acc[3];
                int dcol = jt*16 + c;
                xc_[(4*q+0)*72 + dcol] = (__bf16)silu_f(xc0);
                xc_[(4*q+1)*72 + dcol] = (__bf16)silu_f(xc1);
                xc_[(4*q+2)*72 + dcol] = (__bf16)silu_f(xc2);
                xc_[(4*q+3)*72 + dcol] = (__bf16)silu_f(xc3);
            } else {
                int dcol = (jt-4)*16 + c;
                #pragma unroll
                for (int t = 0; t < 4; ++t)
                    sz_[(4*q+t)*72 + dcol] = (__bf16)silu_f(acc[t]);
            }
        }

        // ---- A2 frags
        bf16x8 A2[2];
        #pragma unroll
        for (int ks = 0; ks < 2; ++ks)
            A2[ks] = *(const bf16x8*)&xc_[c*72 + ks*32 + q*8];

        // ---- GEMM2: dbl[m][r]
        f32x4 dacc[3] = {{0,0,0,0},{0,0,0,0},{0,0,0,0}};
        #pragma unroll
        for (int ks = 0; ks < 2; ++ks) {
            dacc[0] = __builtin_amdgcn_mfma_f32_16x16x32_bf16(A2[ks], B2f[ks][0], dacc[0], 0,0,0);
            dacc[1] = __builtin_amdgcn_mfma_f32_16x16x32_bf16(A2[ks], B2f[ks][1], dacc[1], 0,0,0);
            dacc[2] = __builtin_amdgcn_mfma_f32_16x16x32_bf16(A2[ks], B2f[ks][2], dacc[2], 0,0,0);
        }
        // stage dbl, mixed layout per row m (80B):
        //   f32 dt[2] at f32-idx m*20+2..3
        //   bf16 B[16] at bf16-idx m*40+8..23   (r-2 = s for r in 2..17)
        //   bf16 C[16] at bf16-idx m*40+24..39  (r-18 = s for r in 18..33)
        #pragma unroll
        for (int t = 0; t < 4; ++t) {
            const int m = 4*q + t;
            // rt = 0: r = c
            if (c < 2) db_[m*20 + 2 + c] = dacc[0][t];
            else       dbh[m*40 + 8 + (c-2)] = (__bf16)dacc[0][t];
            // rt = 1: r = 16+c
            if (c < 2) dbh[m*40 + 8 + 14 + c] = (__bf16)dacc[1][t];
            else       dbh[m*40 + 24 + (c-2)] = (__bf16)dacc[1][t];
            // rt = 2: r = 32+c (only c<2 real)
            if (c < 2) dbh[m*40 + 24 + 14 + c] = (__bf16)dacc[2][t];
        }

        // ---- selective scan, lane = d, rows sequential; packed bf16 B/C
        #pragma unroll
        for (int r = 0; r < 4; ++r) {
            f32x2 h2[8];
            #pragma unroll
            for (int s = 0; s < 8; ++s) h2[s] = (f32x2){0.f, 0.f};
            #pragma unroll
            for (int t = 0; t < 4; ++t) {
                const int m = 4*r + t;
                float2 dtv = *(const float2*)&db_[m*20 + 2];
                float p  = fmaf(dtv.y, dtw.y, fmaf(dtv.x, dtw.x, dtbv));
                float ex = __expf(p);
                float t1 = 1.f + ex;
                float e1 = __builtin_amdgcn_rcpf(t1);       // exp(-softplus(p))
                float delta = (p > 15.f) ? p : __logf(t1);  // softplus(p)
                float u  = (float)xc_[m*72 + lane];
                float sz = (float)sz_[m*72 + lane];
                const float bu = delta * u;
                const f32x2 bu2 = {bu, bu};

                f32x2 accA = {0.f, 0.f}, accB = {0.f, 0.f};
                if (fastA) {
                    // B/C: 4 x b128 (8 bf16-pairs each for B then C)
                    const uint4* bp = (const uint4*)&db_[m*20 + 4];
                    uint4 b0 = bp[0], b1 = bp[1], c0 = bp[2], c1 = bp[3];
                    f32x2 Bp[8] = {upk(b0.x), upk(b0.y), upk(b0.z), upk(b0.w),
                                   upk(b1.x), upk(b1.y), upk(b1.z), upk(b1.w)};
                    f32x2 Cp[8] = {upk(c0.x), upk(c0.y), upk(c0.z), upk(c0.w),
                                   upk(c1.x), upk(c1.y), upk(c1.z), upk(c1.w)};
                    float e2 = e1*e1;
                    f32x2 dc = {e1, e2};
                    const f32x2 ee = {e2, e2};
                    #pragma unroll
                    for (int i = 0; i < 8; ++i) {
                        h2[i] = pk_fma(dc, h2[i], pk_mul(bu2, Bp[i]));
                        if (i & 1) accB = pk_fma(h2[i], Cp[i], accB);
                        else       accA = pk_fma(h2[i], Cp[i], accA);
                        dc = pk_mul(dc, ee);
                    }
                } else {
                    #pragma unroll
                    for (int s = 0; s < 16; ++s) {
                        float aAbs = __expf(A_log[lane*16 + s]);
                        float dA = __expf(-delta * aAbs);
                        float Bm = (float)dbh[m*40 + 8 + s];
                        float Cm = (float)dbh[m*40 + 24 + s];
                        float hv = dA * h2[s>>1][s&1] + bu * Bm;
                        h2[s>>1][s&1] = hv;
                        if (s & 1) accB[0] += hv * Cm; else accA[0] += hv * Cm;
                    }
                }
                float acc = (accA[0] + accA[1]) + (accB[0] + accB[1]);
                float y = fmaf(u, Dd, acc) * sz;
                xc_[m*72 + lane] = (__bf16)y;    // overlay xc with gated y
            }
        }

        // ---- A3 frags + GEMM3 + store + stats
        bf16x8 A3[2];
        #pragma unroll
        for (int ks = 0; ks < 2; ++ks)
            A3[ks] = *(const bf16x8*)&xc_[c*72 + ks*32 + q*8];

        float s1 = 0.f, s2 = 0.f;
        float* orow = xr + n0*128;
        #pragma unroll
        for (int jt = 0; jt < 2; ++jt) {
            f32x4 oacc = {0.f, 0.f, 0.f, 0.f};
            oacc = __builtin_amdgcn_mfma_f32_16x16x32_bf16(A3[0], B3p[(jt*2+0)*64 + lane], oacc, 0,0,0);
            oacc = __builtin_amdgcn_mfma_f32_16x16x32_bf16(A3[1], B3p[(jt*2+1)*64 + lane], oacc, 0,0,0);
            #pragma unroll
            for (int t = 0; t < 4; ++t) {
                orow[(4*q+t)*32 + jt*16 + c] = oacc[t];
                s1 += oacc[t];
                s2 += oacc[t]*oacc[t];
            }
        }
        #pragma unroll
        for (int off = 32; off > 0; off >>= 1) {
            s1 += __shfl_xor(s1, off, 64);
            s2 += __shfl_xor(s2, off, 64);
        }
        if (lane == 0) {
            atomicAdd(&S1[tile >> 5], s1);
            atomicAdd(&S2[tile >> 5], s2);
        }
    }
}

// ---------------------------------------------------------------------------
// K2: SE MLP gate + analytic GroupNorm stats -> per-(b,c) alpha/beta (1 block)
// ---------------------------------------------------------------------------
__global__ __launch_bounds__(256) void k_se(
    const float* __restrict__ S1, const float* __restrict__ S2,
    const float* __restrict__ se1_w,  // (32,128)
    const float* __restrict__ se2_w,  // (128,32)
    const float* __restrict__ gn_w, const float* __restrict__ gn_b,
    float* __restrict__ alpha, float* __restrict__ beta)
{
    __shared__ float sp[256], sh[64], sg[256], st1[256], st2[256];
    __shared__ float smu[8], sinv[8];
    const int tid = threadIdx.x;

    sp[tid] = S1[tid] * (1.f/16384.f);
    __syncthreads();

    if (tid < 64) {
        int b = tid >> 5, j = tid & 31;
        float acc = 0.f;
        for (int cc = 0; cc < 128; ++cc) acc += sp[b*128 + cc] * se1_w[j*128 + cc];
        sh[tid] = silu_f(acc);
    }
    __syncthreads();

    {
        int b = tid >> 7, cc = tid & 127;
        float acc = 0.f;
        #pragma unroll
        for (int j = 0; j < 32; ++j) acc += sh[b*32 + j] * se2_w[cc*32 + j];
        float g = __builtin_amdgcn_rcpf(1.f + __expf(-acc));
        sg[tid]  = g;
        st1[tid] = g * S1[tid];
        st2[tid] = g * g * S2[tid];
    }
    __syncthreads();

    if (tid < 8) {
        int b = tid >> 2, gr = tid & 3;
        float m = 0.f, qq = 0.f;
        for (int cc = 0; cc < 32; ++cc) {
            m  += st1[b*128 + gr*32 + cc];
            qq += st2[b*128 + gr*32 + cc];
        }
        const float inv_cnt = 1.f / (32.f * 16384.f);
        m *= inv_cnt; qq *= inv_cnt;
        smu[tid]  = m;
        sinv[tid] = rsqrtf(qq - m*m + 1e-5f);
    }
    __syncthreads();

    {
        int b = tid >> 7, cc = tid & 127;
        int gi = b*4 + (cc >> 5);
        float iv = sinv[gi], mu = smu[gi], g = sg[tid], w = gn_w[cc];
        alpha[tid] = g * iv * w;
        beta[tid]  = gn_b[cc] - mu * iv * w;
    }
}

// ---------------------------------------------------------------------------
// K3: pure streaming: out = silu(alpha*xr + beta) + x   (in-place on d_out)
// ---------------------------------------------------------------------------
__global__ __launch_bounds__(256) void k_final(
    const float* __restrict__ x, float* __restrict__ o,
    const float* __restrict__ alpha, const float* __restrict__ beta)
{
    __shared__ float al[256], be[256];
    const int tid = threadIdx.x;
    al[tid] = alpha[tid];
    be[tid] = beta[tid];
    __syncthreads();

    const int total4 = (2*128*128*128) / 4;
    const float4* x4 = (const float4*)x;
    float4* o4 = (float4*)o;
    for (int i = blockIdx.x*blockDim.x + tid; i < total4;
         i += gridDim.x*blockDim.x) {
        int bc = i >> 12;
        float a = al[bc], b = be[bc];
        float4 v = o4[i], xv = x4[i];
        float u;
        u = a*v.x + b;  v.x = silu_f(u) + xv.x;
        u = a*v.y + b;  v.y = silu_f(u) + xv.y;
        u = a*v.z + b;  v.z = silu_f(u) + xv.z;
        u = a*v.w + b;  v.w = silu_f(u) + xv.w;
        o4[i] = v;
    }
}

extern "C" void kernel_launch(void* const* d_in, const int* in_sizes, int n_in,
                              void* d_out, int out_size, void* d_ws, size_t ws_size,
                              hipStream_t stream) {
    const float* x          = (const float*)d_in[0];
    const float* in_proj_w  = (const float*)d_in[1];
    const float* conv_w     = (const float*)d_in[2];
    const float* conv_b     = (const float*)d_in[3];
    const float* x_proj_w   = (const float*)d_in[4];
    const float* dt_proj_w  = (const float*)d_in[5];
    const float* dt_proj_b  = (const float*)d_in[6];
    const float* A_log      = (const float*)d_in[7];
    const float* Dvec       = (const float*)d_in[8];
    const float* out_proj_w = (const float*)d_in[9];
    const float* se1_w      = (const float*)d_in[10];
    const float* se2_w      = (const float*)d_in[11];
    const float* gn_w       = (const float*)d_in[12];
    const float* gn_b       = (const float*)d_in[13];

    float* out = (float*)d_out;
    float* ws  = (float*)d_ws;
    float* S1 = ws;           // 256
    float* S2 = ws + 256;     // 256
    float* alpha = ws + 512;  // 256
    float* beta  = ws + 768;  // 256

    hipMemsetAsync(ws, 0, 512*sizeof(float), stream);
    k_mamba<<<768, THREADS, 0, stream>>>(x, in_proj_w, conv_w, conv_b, x_proj_w,
                                         dt_proj_w, dt_proj_b, A_log, Dvec,
                                         out_proj_w, out, S1, S2);
    k_se<<<1, THREADS, 0, stream>>>(S1, S2, se1_w, se2_w, gn_w, gn_b, alpha, beta);
    k_final<<<1024, THREADS, 0, stream>>>(x, out, alpha, beta);
}